// Round 1
// baseline (250.474 us; speedup 1.0000x reference)
//
#include <hip/hip_runtime.h>

#define Bz 2
#define Sz 2048
#define Dz 1024
#define Hz 16
#define HSz 64
#define Mz 4096
#define NEGB (-1e30f)

typedef _Float16 f16;
typedef _Float16 f16x8 __attribute__((ext_vector_type(8)));
typedef _Float16 f16x4 __attribute__((ext_vector_type(4)));
typedef float f32x4 __attribute__((ext_vector_type(4)));

#define MFMA(a, b, c) __builtin_amdgcn_mfma_f32_16x16x32_f16((a), (b), (c), 0, 0, 0)

__device__ __forceinline__ void gload16(const void* g, void* l) {
  __builtin_amdgcn_global_load_lds(
      (const __attribute__((address_space(1))) unsigned int*)(unsigned long long)g,
      (__attribute__((address_space(3))) unsigned int*)(unsigned int)(unsigned long long)l,
      16, 0, 0);
}

// ---------------- fp32 -> fp16 convert ----------------
__global__ __launch_bounds__(256) void k_cvt(const float* __restrict__ in,
                                             f16* __restrict__ out, int n) {
  int i = (blockIdx.x * 256 + threadIdx.x) * 4;
  if (i < n) {
    f32x4 v = *reinterpret_cast<const f32x4*>(in + i);
    f16x4 o;
    o[0] = (f16)v[0]; o[1] = (f16)v[1]; o[2] = (f16)v[2]; o[3] = (f16)v[3];
    *reinterpret_cast<f16x4*>(out + i) = o;
  }
}

// ---------------- W [K][N] fp32 -> Wt hi/lo [N][K] fp16 ----------------
__global__ __launch_bounds__(256) void k_wsplit(const float* __restrict__ W,
                                                f16* __restrict__ Thi,
                                                f16* __restrict__ Tlo) {
  __shared__ float t[32][33];
  const int tx = threadIdx.x & 31, ty = threadIdx.x >> 5;
  const int n0 = blockIdx.x * 32, k0 = blockIdx.y * 32;
#pragma unroll
  for (int r = 0; r < 4; ++r)
    t[ty * 4 + r][tx] = W[(size_t)(k0 + ty * 4 + r) * Dz + n0 + tx];
  __syncthreads();
#pragma unroll
  for (int r = 0; r < 4; ++r) {
    float v = t[tx][ty * 4 + r];
    int n = n0 + ty * 4 + r, k = k0 + tx;
    f16 hi = (f16)v;
    Thi[(size_t)n * Dz + k] = hi;
    Tlo[(size_t)n * Dz + k] = (f16)(v - (float)hi);
  }
}

// ---------------- GEMM: C[M,N] = A[M,K] * (Bhi+Blo)^T + bias ----------------
// A: [4096][1024] f16 row-major.  Bhi/Blo: [N=1024][K=1024] f16 (transposed W).
// MODE 0: write f16 [b][h][token][hs]   (Q,K)
// MODE 1: write f16 [b][h][hs][token]   (V transposed)
// MODE 2: write f32 d_out, * q_mask[row]
#define BMg 128
#define BNg 64
#define BKg 32

template <int MODE>
__global__ __launch_bounds__(256) void k_gemm(
    const f16* __restrict__ A, const f16* __restrict__ Bhi,
    const f16* __restrict__ Blo, const float* __restrict__ bias,
    f16* __restrict__ outh, float* __restrict__ outf,
    const int* __restrict__ qmask) {
  __shared__ f16 As[BMg * BKg];
  __shared__ f16 Bh[BNg * BKg];
  __shared__ f16 Bl[BNg * BKg];
  const int t = threadIdx.x, lane = t & 63, wv = t >> 6;
  const int ll = lane & 15, lh = lane >> 4;
  const int m0 = blockIdx.y * BMg, n0 = blockIdx.x * BNg;
  const int wr = wv >> 1, wc = wv & 1;
  f32x4 acc[4][2] = {};

  for (int k0 = 0; k0 < Dz; k0 += BKg) {
    __syncthreads();
#pragma unroll
    for (int j = 0; j < 2; ++j) {
      int c = (wv * 2 + j) * 64 + lane;
      gload16(A + (size_t)(m0 + (c >> 2)) * Dz + k0 + (c & 3) * 8,
              (char*)As + (wv * 2 + j) * 1024);
    }
    {
      int c = wv * 64 + lane;
      const size_t go = (size_t)(n0 + (c >> 2)) * Dz + k0 + (c & 3) * 8;
      gload16(Bhi + go, (char*)Bh + wv * 1024);
      gload16(Blo + go, (char*)Bl + wv * 1024);
    }
    __syncthreads();

    f16x8 af[4], fbh[2], fbl[2];
#pragma unroll
    for (int r = 0; r < 4; ++r)
      af[r] = *reinterpret_cast<const f16x8*>(&As[(wr * 64 + r * 16 + ll) * BKg + lh * 8]);
#pragma unroll
    for (int c = 0; c < 2; ++c) {
      int o = (wc * 32 + c * 16 + ll) * BKg + lh * 8;
      fbh[c] = *reinterpret_cast<const f16x8*>(&Bh[o]);
      fbl[c] = *reinterpret_cast<const f16x8*>(&Bl[o]);
    }
#pragma unroll
    for (int r = 0; r < 4; ++r)
#pragma unroll
      for (int c = 0; c < 2; ++c) {
        acc[r][c] = MFMA(af[r], fbh[c], acc[r][c]);
        acc[r][c] = MFMA(af[r], fbl[c], acc[r][c]);
      }
  }

#pragma unroll
  for (int r = 0; r < 4; ++r)
#pragma unroll
    for (int c = 0; c < 2; ++c)
#pragma unroll
      for (int i = 0; i < 4; ++i) {
        int row = m0 + wr * 64 + r * 16 + lh * 4 + i;
        int col = n0 + wc * 32 + c * 16 + ll;
        float v = acc[r][c][i] + bias[col];
        if (MODE == 0) {
          outh[((size_t)((row >> 11) * Hz + (col >> 6))) * (Sz * HSz) +
               (size_t)(row & (Sz - 1)) * HSz + (col & 63)] = (f16)v;
        } else if (MODE == 1) {
          outh[((size_t)((row >> 11) * Hz + (col >> 6))) * (HSz * Sz) +
               (size_t)(col & 63) * Sz + (row & (Sz - 1))] = (f16)v;
        } else {
          outf[(size_t)row * Dz + col] = v * (float)qmask[row];
        }
      }
}

// ---------------- flash attention per (b,h) ----------------
// Q,K: [bh][token][hs] f16; Vt: [bh][hs][token] f16; out attnA: [token][h*64+hs] f16
#define QB 128
#define KBc 64

__global__ __launch_bounds__(256) void k_attn(
    const f16* __restrict__ Q, const f16* __restrict__ K,
    const f16* __restrict__ Vt, const int* __restrict__ vmask,
    f16* __restrict__ attnA) {
  __shared__ f16 Kl[KBc][72];
  __shared__ f16 Vl[HSz][72];
  __shared__ f16 Pl[QB][72];
  __shared__ float vmf[KBc];
  const int t = threadIdx.x, lane = t & 63, wv = t >> 6;
  const int ll = lane & 15, lh = lane >> 4;
  const int bh = blockIdx.y, b = bh >> 4, h = bh & 15;
  const int q0 = blockIdx.x * QB;
  const size_t base = (size_t)bh * Sz * HSz;

  f16x8 qf[2][2];
  const f16* Qb = Q + base + (size_t)(q0 + wv * 32) * HSz;
#pragma unroll
  for (int rg = 0; rg < 2; ++rg)
#pragma unroll
    for (int kf = 0; kf < 2; ++kf)
      qf[rg][kf] = *reinterpret_cast<const f16x8*>(
          &Qb[(rg * 16 + ll) * HSz + kf * 32 + lh * 8]);

  f32x4 acc_o[2][4] = {};
  float m_run[2][4], l_run[2][4];
#pragma unroll
  for (int rg = 0; rg < 2; ++rg)
#pragma unroll
    for (int i = 0; i < 4; ++i) { m_run[rg][i] = NEGB; l_run[rg][i] = 0.f; }

  for (int key0 = 0; key0 < Sz; key0 += KBc) {
    __syncthreads();
#pragma unroll
    for (int p = 0; p < 2; ++p) {
      int c = p * 256 + t;
      int row = c >> 3, off = (c & 7) * 8;
      *reinterpret_cast<f16x8*>(&Kl[row][off]) =
          *reinterpret_cast<const f16x8*>(&K[base + (size_t)(key0 + row) * HSz + off]);
      *reinterpret_cast<f16x8*>(&Vl[row][off]) =
          *reinterpret_cast<const f16x8*>(&Vt[base + (size_t)row * Sz + key0 + off]);
    }
    if (t < KBc) vmf[t] = vmask[b * Sz + key0 + t] ? 1.f : 0.f;
    __syncthreads();

    // S = Q K^T
    f16x8 kb[4][2];
#pragma unroll
    for (int cf = 0; cf < 4; ++cf)
#pragma unroll
      for (int kf = 0; kf < 2; ++kf)
        kb[cf][kf] = *reinterpret_cast<const f16x8*>(&Kl[cf * 16 + ll][kf * 32 + lh * 8]);
    f32x4 sa[2][4] = {};
#pragma unroll
    for (int rg = 0; rg < 2; ++rg)
#pragma unroll
      for (int cf = 0; cf < 4; ++cf)
#pragma unroll
        for (int kf = 0; kf < 2; ++kf)
          sa[rg][cf] = MFMA(qf[rg][kf], kb[cf][kf], sa[rg][cf]);

    float vmc[4];
#pragma unroll
    for (int cf = 0; cf < 4; ++cf) vmc[cf] = vmf[cf * 16 + ll];

    // online softmax (rows replicated across the 16 lanes of each group)
#pragma unroll
    for (int rg = 0; rg < 2; ++rg)
#pragma unroll
      for (int i = 0; i < 4; ++i) {
        float se[4];
        float mx = NEGB;
#pragma unroll
        for (int cf = 0; cf < 4; ++cf) {
          float s = sa[rg][cf][i] * 0.125f;
          se[cf] = vmc[cf] > 0.5f ? s : NEGB;
          mx = fmaxf(mx, se[cf]);
        }
#pragma unroll
        for (int o = 1; o < 16; o <<= 1)
          mx = fmaxf(mx, __shfl_xor(mx, o, 64));
        float nm = fmaxf(m_run[rg][i], mx);
        float sc = __expf(m_run[rg][i] - nm);
        float pv[4], rs = 0.f;
#pragma unroll
        for (int cf = 0; cf < 4; ++cf) {
          pv[cf] = vmc[cf] * __expf(se[cf] - nm);
          rs += pv[cf];
        }
#pragma unroll
        for (int o = 1; o < 16; o <<= 1) rs += __shfl_xor(rs, o, 64);
        m_run[rg][i] = nm;
        l_run[rg][i] = l_run[rg][i] * sc + rs;
#pragma unroll
        for (int cf = 0; cf < 4; ++cf) acc_o[rg][cf][i] *= sc;
        int prow = wv * 32 + rg * 16 + lh * 4 + i;
#pragma unroll
        for (int cf = 0; cf < 4; ++cf)
          Pl[prow][cf * 16 + ll] = (f16)pv[cf];
      }

    // O += P V
    f16x8 pa[2][2], vb[4][2];
#pragma unroll
    for (int cf = 0; cf < 4; ++cf)
#pragma unroll
      for (int ks = 0; ks < 2; ++ks)
        vb[cf][ks] = *reinterpret_cast<const f16x8*>(&Vl[cf * 16 + ll][ks * 32 + lh * 8]);
#pragma unroll
    for (int rg = 0; rg < 2; ++rg)
#pragma unroll
      for (int ks = 0; ks < 2; ++ks)
        pa[rg][ks] = *reinterpret_cast<const f16x8*>(
            &Pl[wv * 32 + rg * 16 + ll][ks * 32 + lh * 8]);
#pragma unroll
    for (int rg = 0; rg < 2; ++rg)
#pragma unroll
      for (int cf = 0; cf < 4; ++cf)
#pragma unroll
        for (int ks = 0; ks < 2; ++ks)
          acc_o[rg][cf] = MFMA(pa[rg][ks], vb[cf][ks], acc_o[rg][cf]);
  }

#pragma unroll
  for (int rg = 0; rg < 2; ++rg)
#pragma unroll
    for (int i = 0; i < 4; ++i) {
      float inv = 1.f / fmaxf(l_run[rg][i], 1e-37f);
      int token = q0 + wv * 32 + rg * 16 + lh * 4 + i;
      size_t rb = ((size_t)(b * Sz + token)) * (Hz * HSz) + h * HSz;
#pragma unroll
      for (int cf = 0; cf < 4; ++cf)
        attnA[rb + cf * 16 + ll] = (f16)(acc_o[rg][cf][i] * inv);
    }
}

extern "C" void kernel_launch(void* const* d_in, const int* in_sizes, int n_in,
                              void* d_out, int out_size, void* d_ws, size_t ws_size,
                              hipStream_t stream) {
  const float* query = (const float*)d_in[0];
  const float* key   = (const float*)d_in[1];
  const float* value = (const float*)d_in[2];
  const float* Wq = (const float*)d_in[3];
  const float* bq = (const float*)d_in[4];
  const float* Wk = (const float*)d_in[5];
  const float* bk = (const float*)d_in[6];
  const float* Wv = (const float*)d_in[7];
  const float* bv = (const float*)d_in[8];
  const float* Wo = (const float*)d_in[9];
  const float* bo = (const float*)d_in[10];
  const int* qm = (const int*)d_in[11];
  const int* vm = (const int*)d_in[12];

  // workspace layout (f16 elements)
  f16* Xq  = (f16*)d_ws;
  f16* Xk  = Xq + 4194304;
  f16* Xv  = Xk + 4194304;
  f16* Wqh = Xv + 4194304;
  f16* Wql = Wqh + 1048576;
  f16* Wkh = Wql + 1048576;
  f16* Wkl = Wkh + 1048576;
  f16* Wvh = Wkl + 1048576;
  f16* Wvl = Wvh + 1048576;
  f16* Woh = Wvl + 1048576;
  f16* Wol = Woh + 1048576;
  f16* Qh  = Wol + 1048576;
  f16* Kh  = Qh + 4194304;
  f16* Vth = Kh + 4194304;
  f16* Ah  = Vth + 4194304;   // total 72 MB

  k_cvt<<<4096, 256, 0, stream>>>(query, Xq, Mz * Dz);
  k_cvt<<<4096, 256, 0, stream>>>(key,   Xk, Mz * Dz);
  k_cvt<<<4096, 256, 0, stream>>>(value, Xv, Mz * Dz);

  dim3 wg(32, 32);
  k_wsplit<<<wg, 256, 0, stream>>>(Wq, Wqh, Wql);
  k_wsplit<<<wg, 256, 0, stream>>>(Wk, Wkh, Wkl);
  k_wsplit<<<wg, 256, 0, stream>>>(Wv, Wvh, Wvl);
  k_wsplit<<<wg, 256, 0, stream>>>(Wo, Woh, Wol);

  dim3 gg(Dz / BNg, Mz / BMg);  // (16, 32)
  k_gemm<0><<<gg, 256, 0, stream>>>(Xq, Wqh, Wql, bq, Qh, nullptr, nullptr);
  k_gemm<0><<<gg, 256, 0, stream>>>(Xk, Wkh, Wkl, bk, Kh, nullptr, nullptr);
  k_gemm<1><<<gg, 256, 0, stream>>>(Xv, Wvh, Wvl, bv, Vth, nullptr, nullptr);

  dim3 ag(Sz / QB, Bz * Hz);    // (16, 32)
  k_attn<<<ag, 256, 0, stream>>>(Qh, Kh, Vth, vm, Ah);

  k_gemm<2><<<gg, 256, 0, stream>>>(Ah, Woh, Wol, bo, nullptr, (float*)d_out, qm);
}

// Round 3
// 184.698 us; speedup vs baseline: 1.3561x; 1.3561x over previous
//
#include <hip/hip_runtime.h>

#define Bz 2
#define Sz 2048
#define Dz 1024
#define Hz 16
#define HSz 64
#define Mz 4096
#define NEGB (-1e30f)
#define QSCALE (0.125f * 1.44269504088896f)  // fold 1/sqrt(64) and log2(e) into Q

typedef _Float16 f16;
typedef _Float16 f16x8 __attribute__((ext_vector_type(8)));
typedef _Float16 f16x4 __attribute__((ext_vector_type(4)));
typedef float f32x4 __attribute__((ext_vector_type(4)));

#define MFMA32(a, b, c) __builtin_amdgcn_mfma_f32_16x16x32_f16((a), (b), (c), 0, 0, 0)
#define MFMA16(a, b, c) __builtin_amdgcn_mfma_f32_16x16x16f16((a), (b), (c), 0, 0, 0)
#define EXP2(x) __builtin_amdgcn_exp2f(x)

__device__ __forceinline__ void gload16(const void* g, void* l) {
  __builtin_amdgcn_global_load_lds(
      (const __attribute__((address_space(1))) unsigned int*)(unsigned long long)g,
      (__attribute__((address_space(3))) unsigned int*)(unsigned int)(unsigned long long)l,
      16, 0, 0);
}
__device__ __forceinline__ void gload4(const void* g, void* l) {
  __builtin_amdgcn_global_load_lds(
      (const __attribute__((address_space(1))) unsigned int*)(unsigned long long)g,
      (__attribute__((address_space(3))) unsigned int*)(unsigned int)(unsigned long long)l,
      4, 0, 0);
}

// ---------------- fp32 -> fp16 convert ----------------
__global__ __launch_bounds__(256) void k_cvt(const float* __restrict__ in,
                                             f16* __restrict__ out, int n) {
  int i = (blockIdx.x * 256 + threadIdx.x) * 4;
  if (i < n) {
    f32x4 v = *reinterpret_cast<const f32x4*>(in + i);
    f16x4 o;
    o[0] = (f16)v[0]; o[1] = (f16)v[1]; o[2] = (f16)v[2]; o[3] = (f16)v[3];
    *reinterpret_cast<f16x4*>(out + i) = o;
  }
}

// ---------------- v_mask -> f32 additive bias (exp2 domain) ----------------
__global__ __launch_bounds__(256) void k_mask(const int* __restrict__ vm,
                                              float* __restrict__ out) {
  int i = blockIdx.x * 256 + threadIdx.x;
  if (i < Bz * Sz) out[i] = vm[i] ? 0.f : NEGB;
}

// ---------------- W [K][N] fp32 -> Wt (hi[,lo]) [N][K] fp16 ----------------
template <bool LO>
__global__ __launch_bounds__(256) void k_wsplit(const float* __restrict__ W,
                                                f16* __restrict__ Thi,
                                                f16* __restrict__ Tlo) {
  __shared__ float t[32][33];
  const int tx = threadIdx.x & 31, ty = threadIdx.x >> 5;
  const int n0 = blockIdx.x * 32, k0 = blockIdx.y * 32;
#pragma unroll
  for (int r = 0; r < 4; ++r)
    t[ty * 4 + r][tx] = W[(size_t)(k0 + ty * 4 + r) * Dz + n0 + tx];
  __syncthreads();
#pragma unroll
  for (int r = 0; r < 4; ++r) {
    float v = t[tx][ty * 4 + r];
    int n = n0 + ty * 4 + r, k = k0 + tx;
    f16 hi = (f16)v;
    Thi[(size_t)n * Dz + k] = hi;
    if (LO) Tlo[(size_t)n * Dz + k] = (f16)(v - (float)hi);
  }
}

// ---------------- GEMM: C[M,N] = A[M,K] * Bt^T + bias ----------------
// MODE 0: write f16 [b][h][token][hs] (Q: oscale=QSCALE; K: oscale=1)
// MODE 1: write f16 [b][h][hs][token] (V transposed)
// MODE 2: write f32 d_out, * q_mask[row]
#define BMg 128
#define BNg 64
#define BKg 32

template <int MODE, bool LO>
__global__ __launch_bounds__(256) void k_gemm(
    const f16* __restrict__ A, const f16* __restrict__ Bhi,
    const f16* __restrict__ Blo, const float* __restrict__ bias,
    f16* __restrict__ outh, float* __restrict__ outf,
    const int* __restrict__ qmask, float oscale) {
  __shared__ f16 As[BMg * BKg];
  __shared__ f16 Bh[BNg * BKg];
  __shared__ f16 Bl[LO ? BNg * BKg : 8];
  const int t = threadIdx.x, lane = t & 63, wv = t >> 6;
  const int ll = lane & 15, lh = lane >> 4;
  const int m0 = blockIdx.y * BMg, n0 = blockIdx.x * BNg;
  const int wr = wv >> 1, wc = wv & 1;
  f32x4 acc[4][2] = {};

  for (int k0 = 0; k0 < Dz; k0 += BKg) {
    __syncthreads();
#pragma unroll
    for (int j = 0; j < 2; ++j) {
      int c = (wv * 2 + j) * 64 + lane;
      gload16(A + (size_t)(m0 + (c >> 2)) * Dz + k0 + (c & 3) * 8,
              (char*)As + (wv * 2 + j) * 1024);
    }
    {
      int c = wv * 64 + lane;
      const size_t go = (size_t)(n0 + (c >> 2)) * Dz + k0 + (c & 3) * 8;
      gload16(Bhi + go, (char*)Bh + wv * 1024);
      if (LO) gload16(Blo + go, (char*)Bl + wv * 1024);
    }
    __syncthreads();

    f16x8 af[4], fbh[2], fbl[2];
#pragma unroll
    for (int r = 0; r < 4; ++r)
      af[r] = *reinterpret_cast<const f16x8*>(&As[(wr * 64 + r * 16 + ll) * BKg + lh * 8]);
#pragma unroll
    for (int c = 0; c < 2; ++c) {
      int o = (wc * 32 + c * 16 + ll) * BKg + lh * 8;
      fbh[c] = *reinterpret_cast<const f16x8*>(&Bh[o]);
      if (LO) fbl[c] = *reinterpret_cast<const f16x8*>(&Bl[o]);
    }
#pragma unroll
    for (int r = 0; r < 4; ++r)
#pragma unroll
      for (int c = 0; c < 2; ++c) {
        acc[r][c] = MFMA32(af[r], fbh[c], acc[r][c]);
        if (LO) acc[r][c] = MFMA32(af[r], fbl[c], acc[r][c]);
      }
  }

#pragma unroll
  for (int r = 0; r < 4; ++r)
#pragma unroll
    for (int c = 0; c < 2; ++c)
#pragma unroll
      for (int i = 0; i < 4; ++i) {
        int row = m0 + wr * 64 + r * 16 + lh * 4 + i;
        int col = n0 + wc * 32 + c * 16 + ll;
        float v = (acc[r][c][i] + bias[col]) * oscale;
        if (MODE == 0) {
          outh[((size_t)((row >> 11) * Hz + (col >> 6))) * (Sz * HSz) +
               (size_t)(row & (Sz - 1)) * HSz + (col & 63)] = (f16)v;
        } else if (MODE == 1) {
          outh[((size_t)((row >> 11) * Hz + (col >> 6))) * (HSz * Sz) +
               (size_t)(col & 63) * Sz + (row & (Sz - 1))] = (f16)v;
        } else {
          outf[(size_t)row * Dz + col] = v * (float)qmask[row];
        }
      }
}

// ---------------- flash attention, S^T structure ----------------
// Q,K: [bh][token][hs] f16; Vt: [bh][hs][token] f16; vmb: [b][token] f32 bias.
// Per wave: 16 queries (q = ll). S^T = mfma32(K_frag, Q_frag): lane holds 16
// key-scores (4 cf x 4 i, key = 16cf+4lh+i) of ONE query. Softmax in-register
// (15 fmax + 2 shfl). P^T D-layout == B-layout of mfma 16x16x16 -> PV directly.
#define QB 64
#define KBc 64
#define NT (Sz / KBc)

__global__ __launch_bounds__(256, 4) void k_attn(
    const f16* __restrict__ Q, const f16* __restrict__ K,
    const f16* __restrict__ Vt, const float* __restrict__ vmb,
    f16* __restrict__ attnA) {
  __shared__ f16 Kl[2][KBc * 64];
  __shared__ f16 Vl[2][HSz * 64];
  __shared__ float mbl[2][KBc];
  const int t = threadIdx.x, lane = t & 63, wv = t >> 6;
  const int ll = lane & 15, lh = lane >> 4;
  const int bh = blockIdx.y, b = bh >> 4, h = bh & 15;
  const int q0 = blockIdx.x * QB;
  const size_t base = (size_t)bh * Sz * HSz;

  // Q B-fragments: lane holds query q0+wv*16+ll, hs slice lh*8 (+32 for kf=1)
  f16x8 qf[2];
  {
    const f16* Qb = Q + base + (size_t)(q0 + wv * 16 + ll) * HSz;
    qf[0] = *reinterpret_cast<const f16x8*>(&Qb[lh * 8]);
    qf[1] = *reinterpret_cast<const f16x8*>(&Qb[32 + lh * 8]);
  }

  f32x4 acc[4] = {};
  float m_run = NEGB, l_run = 0.f;

  // stage tile key0 into buffer buf (linear LDS dest, XOR-swizzled source)
  auto stage = [&](int key0, int buf) {
#pragma unroll
    for (int j = 0; j < 2; ++j) {
      int c = (wv * 2 + j) * 64 + lane;
      int r = c >> 3, p = c & 7, ps = (p ^ (r & 7)) * 8;
      gload16(K + base + (size_t)(key0 + r) * HSz + ps, (char*)&Kl[buf][0] + c * 16);
      gload16(Vt + base + (size_t)r * Sz + key0 + ps, (char*)&Vl[buf][0] + c * 16);
    }
    if (wv == 0)
      gload4(vmb + b * Sz + key0 + lane, (char*)&mbl[buf][0] + lane * 4);
  };

  stage(0, 0);
  __syncthreads();

#pragma unroll 2
  for (int kt = 0; kt < NT; ++kt) {
    const int cur = kt & 1;
    if (kt + 1 < NT) stage((kt + 1) * KBc, cur ^ 1);

    // S^T = K * Q^T  (A = K fragment from LDS, B = Q fragment in regs)
    f32x4 sa[4] = {};
    __builtin_amdgcn_s_setprio(1);
#pragma unroll
    for (int cf = 0; cf < 4; ++cf) {
      const int row = cf * 16 + ll;
      const f16* kr = &Kl[cur][row * 64];
      f16x8 ka0 = *reinterpret_cast<const f16x8*>(&kr[(lh ^ (ll & 7)) * 8]);
      f16x8 ka1 = *reinterpret_cast<const f16x8*>(&kr[((4 + lh) ^ (ll & 7)) * 8]);
      sa[cf] = MFMA32(ka0, qf[0], sa[cf]);
      sa[cf] = MFMA32(ka1, qf[1], sa[cf]);
    }
    __builtin_amdgcn_s_setprio(0);

    // masked scores + in-register online softmax (one query per lane)
    float s[4][4];
    float mx = NEGB;
#pragma unroll
    for (int cf = 0; cf < 4; ++cf) {
      f32x4 mb = *reinterpret_cast<const f32x4*>(&mbl[cur][cf * 16 + lh * 4]);
#pragma unroll
      for (int i = 0; i < 4; ++i) {
        s[cf][i] = sa[cf][i] + mb[i];
        mx = fmaxf(mx, s[cf][i]);
      }
    }
    mx = fmaxf(mx, __shfl_xor(mx, 16));
    mx = fmaxf(mx, __shfl_xor(mx, 32));
    const float nm = fmaxf(m_run, mx);
    const float sc = EXP2(m_run - nm);
    float rs = 0.f;
    f16x4 pb[4];
#pragma unroll
    for (int cf = 0; cf < 4; ++cf) {
      float p0 = EXP2(s[cf][0] - nm), p1 = EXP2(s[cf][1] - nm);
      float p2 = EXP2(s[cf][2] - nm), p3 = EXP2(s[cf][3] - nm);
      rs += (p0 + p1) + (p2 + p3);
      pb[cf][0] = (f16)p0; pb[cf][1] = (f16)p1;
      pb[cf][2] = (f16)p2; pb[cf][3] = (f16)p3;
    }
    rs += __shfl_xor(rs, 16);
    rs += __shfl_xor(rs, 32);
    m_run = nm;
    l_run = l_run * sc + rs;
#pragma unroll
    for (int hf = 0; hf < 4; ++hf)
#pragma unroll
      for (int i = 0; i < 4; ++i) acc[hf][i] *= sc;

    // O^T += V^T * P^T  (16x16x16: P^T D-layout == B-layout, no data movement)
    __builtin_amdgcn_s_setprio(1);
#pragma unroll
    for (int hf = 0; hf < 4; ++hf) {
      const int row = hf * 16 + ll;
      const f16* vr = &Vl[cur][row * 64];
#pragma unroll
      for (int cf = 0; cf < 4; ++cf) {
        f16x4 va = *reinterpret_cast<const f16x4*>(
            &vr[((2 * cf + (lh >> 1)) ^ (ll & 7)) * 8 + (lh & 1) * 4]);
        acc[hf] = MFMA16(va, pb[cf], acc[hf]);
      }
    }
    __builtin_amdgcn_s_setprio(0);
    __syncthreads();  // drains vmcnt: next buffer staged; cur safe to overwrite
  }

  const float inv = 1.f / fmaxf(l_run, 1e-30f);
  const int q = q0 + wv * 16 + ll;
  f16* orow = attnA + (size_t)(b * Sz + q) * (Hz * HSz) + h * HSz;
#pragma unroll
  for (int hf = 0; hf < 4; ++hf) {
    f16x4 ov;
#pragma unroll
    for (int i = 0; i < 4; ++i) ov[i] = (f16)(acc[hf][i] * inv);
    *reinterpret_cast<f16x4*>(&orow[hf * 16 + 4 * lh]) = ov;
  }
}

extern "C" void kernel_launch(void* const* d_in, const int* in_sizes, int n_in,
                              void* d_out, int out_size, void* d_ws, size_t ws_size,
                              hipStream_t stream) {
  const float* query = (const float*)d_in[0];
  const float* key   = (const float*)d_in[1];
  const float* value = (const float*)d_in[2];
  const float* Wq = (const float*)d_in[3];
  const float* bq = (const float*)d_in[4];
  const float* Wk = (const float*)d_in[5];
  const float* bk = (const float*)d_in[6];
  const float* Wv = (const float*)d_in[7];
  const float* bv = (const float*)d_in[8];
  const float* Wo = (const float*)d_in[9];
  const float* bo = (const float*)d_in[10];
  const int* qm = (const int*)d_in[11];
  const int* vm = (const int*)d_in[12];

  // workspace layout (f16 elements)
  f16* Xq  = (f16*)d_ws;
  f16* Xk  = Xq + 4194304;
  f16* Xv  = Xk + 4194304;
  f16* Wqh = Xv + 4194304;
  f16* Wql = Wqh + 1048576;   // reused as vmbias (f32[4096])
  f16* Wkh = Wql + 1048576;
  f16* Wkl = Wkh + 1048576;   // unused
  f16* Wvh = Wkl + 1048576;
  f16* Wvl = Wvh + 1048576;   // unused
  f16* Woh = Wvl + 1048576;
  f16* Wol = Woh + 1048576;
  f16* Qh  = Wol + 1048576;
  f16* Kh  = Qh + 4194304;
  f16* Vth = Kh + 4194304;
  f16* Ah  = Vth + 4194304;
  float* vmbias = (float*)Wql;

  k_cvt<<<4096, 256, 0, stream>>>(query, Xq, Mz * Dz);
  k_cvt<<<4096, 256, 0, stream>>>(key,   Xk, Mz * Dz);
  k_cvt<<<4096, 256, 0, stream>>>(value, Xv, Mz * Dz);
  k_mask<<<16, 256, 0, stream>>>(vm, vmbias);

  dim3 wg(32, 32);
  k_wsplit<false><<<wg, 256, 0, stream>>>(Wq, Wqh, nullptr);
  k_wsplit<false><<<wg, 256, 0, stream>>>(Wk, Wkh, nullptr);
  k_wsplit<false><<<wg, 256, 0, stream>>>(Wv, Wvh, nullptr);
  k_wsplit<true><<<wg, 256, 0, stream>>>(Wo, Woh, Wol);

  dim3 gg(Dz / BNg, Mz / BMg);  // (16, 32)
  k_gemm<0, false><<<gg, 256, 0, stream>>>(Xq, Wqh, nullptr, bq, Qh, nullptr, nullptr, QSCALE);
  k_gemm<0, false><<<gg, 256, 0, stream>>>(Xk, Wkh, nullptr, bk, Kh, nullptr, nullptr, 1.0f);
  k_gemm<1, false><<<gg, 256, 0, stream>>>(Xv, Wvh, nullptr, bv, Vth, nullptr, nullptr, 1.0f);

  dim3 ag(Sz / QB, Bz * Hz);  // (32, 32)
  k_attn<<<ag, 256, 0, stream>>>(Qh, Kh, Vth, vmbias, Ah);

  k_gemm<2, true><<<gg, 256, 0, stream>>>(Ah, Woh, Wol, bo, nullptr, (float*)d_out, qm, 1.0f);
}

// Round 4
// 157.362 us; speedup vs baseline: 1.5917x; 1.1737x over previous
//
#include <hip/hip_runtime.h>

#define Bz 2
#define Sz 2048
#define Dz 1024
#define Hz 16
#define HSz 64
#define Mz 4096
#define NEGB (-1e30f)
#define QSCALE (0.125f * 1.44269504088896f)  // fold 1/sqrt(64) and log2(e) into Q

typedef _Float16 f16;
typedef _Float16 f16x8 __attribute__((ext_vector_type(8)));
typedef _Float16 f16x4 __attribute__((ext_vector_type(4)));
typedef float f32x4 __attribute__((ext_vector_type(4)));

#define MFMA32(a, b, c) __builtin_amdgcn_mfma_f32_16x16x32_f16((a), (b), (c), 0, 0, 0)
#define MFMA16(a, b, c) __builtin_amdgcn_mfma_f32_16x16x16f16((a), (b), (c), 0, 0, 0)
#define EXP2(x) __builtin_amdgcn_exp2f(x)

__device__ __forceinline__ void gload16(const void* g, void* l) {
  __builtin_amdgcn_global_load_lds(
      (const __attribute__((address_space(1))) unsigned int*)(unsigned long long)g,
      (__attribute__((address_space(3))) unsigned int*)(unsigned int)(unsigned long long)l,
      16, 0, 0);
}
__device__ __forceinline__ void gload4(const void* g, void* l) {
  __builtin_amdgcn_global_load_lds(
      (const __attribute__((address_space(1))) unsigned int*)(unsigned long long)g,
      (__attribute__((address_space(3))) unsigned int*)(unsigned int)(unsigned long long)l,
      4, 0, 0);
}

// ---------------- fp32 -> fp16 convert ----------------
__global__ __launch_bounds__(256) void k_cvt(const float* __restrict__ in,
                                             f16* __restrict__ out, int n) {
  int i = (blockIdx.x * 256 + threadIdx.x) * 4;
  if (i < n) {
    f32x4 v = *reinterpret_cast<const f32x4*>(in + i);
    f16x4 o;
    o[0] = (f16)v[0]; o[1] = (f16)v[1]; o[2] = (f16)v[2]; o[3] = (f16)v[3];
    *reinterpret_cast<f16x4*>(out + i) = o;
  }
}

// ---------------- v_mask -> f32 additive bias (exp2 domain) ----------------
__global__ __launch_bounds__(256) void k_mask(const int* __restrict__ vm,
                                              float* __restrict__ out) {
  int i = blockIdx.x * 256 + threadIdx.x;
  if (i < Bz * Sz) out[i] = vm[i] ? 0.f : NEGB;
}

// ---------------- W [K][N] fp32 -> Wt [N][K] fp16 ----------------
__global__ __launch_bounds__(256) void k_wsplit(const float* __restrict__ W,
                                                f16* __restrict__ Thi) {
  __shared__ float t[32][33];
  const int tx = threadIdx.x & 31, ty = threadIdx.x >> 5;
  const int n0 = blockIdx.x * 32, k0 = blockIdx.y * 32;
#pragma unroll
  for (int r = 0; r < 4; ++r)
    t[ty * 4 + r][tx] = W[(size_t)(k0 + ty * 4 + r) * Dz + n0 + tx];
  __syncthreads();
#pragma unroll
  for (int r = 0; r < 4; ++r) {
    float v = t[tx][ty * 4 + r];
    int n = n0 + ty * 4 + r, k = k0 + tx;
    Thi[(size_t)n * Dz + k] = (f16)v;
  }
}

// ---------------- GEMM: C[M,N] = A[M,K] * Bt^T + bias ----------------
// A: [4096][1024] f16 row-major.  Bt: [N][K] f16 (transposed W).
// 128x128 tile, BK=64, 512 threads (8 waves 2x4), double-buffered LDS,
// XOR-swizzled staging source + swizzled ds_read (conflict-free b128).
// MODE 0: f16 [b][h][token][hs]; MODE 1: f16 [b][h][hs][token]; MODE 2: f32 * qmask
#define BMg 128
#define BNg 128
#define BKg 64

template <int MODE>
__global__ __launch_bounds__(512) void k_gemm(
    const f16* __restrict__ A, const f16* __restrict__ Bt,
    const float* __restrict__ bias, f16* __restrict__ outh,
    float* __restrict__ outf, const int* __restrict__ qmask, float oscale) {
  __shared__ f16 As[2][BMg * BKg];
  __shared__ f16 Bs[2][BNg * BKg];
  const int t = threadIdx.x, lane = t & 63, wv = t >> 6;
  const int ll = lane & 15, lh = lane >> 4;
  const int m0 = blockIdx.y * BMg, n0 = blockIdx.x * BNg;
  const int wr = wv >> 2, wc = wv & 3;  // wave covers 64 rows x 32 cols
  f32x4 acc[4][2] = {};

  auto stage = [&](int kt, int buf) {
    const int k0 = kt * BKg;
#pragma unroll
    for (int j = 0; j < 2; ++j) {
      int c = j * 512 + t;
      int row = c >> 3, p = c & 7;
      int ke = (p ^ (row & 7)) * 8;  // inverse-swizzled source element offset
      gload16(A + (size_t)(m0 + row) * Dz + k0 + ke, (char*)&As[buf][0] + c * 16);
      gload16(Bt + (size_t)(n0 + row) * Dz + k0 + ke, (char*)&Bs[buf][0] + c * 16);
    }
  };

  stage(0, 0);
  __syncthreads();

  for (int kt = 0; kt < Dz / BKg; ++kt) {
    const int cur = kt & 1;
    if (kt + 1 < Dz / BKg) stage(kt + 1, cur ^ 1);

    __builtin_amdgcn_s_setprio(1);
#pragma unroll
    for (int ks = 0; ks < 2; ++ks) {
      f16x8 af[4], bf[2];
#pragma unroll
      for (int fr = 0; fr < 4; ++fr) {
        const int row = wr * 64 + fr * 16 + ll;
        af[fr] = *reinterpret_cast<const f16x8*>(
            &As[cur][row * 64 + (((ks * 4 + lh) ^ (row & 7)) * 8)]);
      }
#pragma unroll
      for (int fc = 0; fc < 2; ++fc) {
        const int col = wc * 32 + fc * 16 + ll;
        bf[fc] = *reinterpret_cast<const f16x8*>(
            &Bs[cur][col * 64 + (((ks * 4 + lh) ^ (col & 7)) * 8)]);
      }
#pragma unroll
      for (int fr = 0; fr < 4; ++fr)
#pragma unroll
        for (int fc = 0; fc < 2; ++fc)
          acc[fr][fc] = MFMA32(af[fr], bf[fc], acc[fr][fc]);
    }
    __builtin_amdgcn_s_setprio(0);
    __syncthreads();  // drains vmcnt: next buffer staged; cur safe to overwrite
  }

#pragma unroll
  for (int fc = 0; fc < 2; ++fc) {
    const int n = n0 + wc * 32 + fc * 16 + ll;
    const float bn = bias[n];
#pragma unroll
    for (int fr = 0; fr < 4; ++fr)
#pragma unroll
      for (int i = 0; i < 4; ++i) {
        const int m = m0 + wr * 64 + fr * 16 + lh * 4 + i;
        float v = (acc[fr][fc][i] + bn) * oscale;
        if (MODE == 0) {
          outh[((size_t)((m >> 11) * Hz + (n >> 6))) * (Sz * HSz) +
               (size_t)(m & (Sz - 1)) * HSz + (n & 63)] = (f16)v;
        } else if (MODE == 1) {
          outh[((size_t)((m >> 11) * Hz + (n >> 6))) * (HSz * Sz) +
               (size_t)(n & 63) * Sz + (m & (Sz - 1))] = (f16)v;
        } else {
          outf[(size_t)m * Dz + n] = v * (float)qmask[m];
        }
      }
  }
}

// ---------------- flash attention, S^T structure ----------------
// Q,K: [bh][token][hs] f16; Vt: [bh][hs][token] f16; vmb: [b][token] f32 bias.
// Per wave: 16 queries (q = ll). S^T = mfma32(K_frag, Q_frag): lane holds 16
// key-scores (4 cf x 4 i, key = 16cf+4lh+i) of ONE query. Softmax in-register
// (defer-max T13). P^T D-layout == B-layout of mfma 16x16x16 -> PV directly.
#define QB 64
#define KBc 64
#define NT (Sz / KBc)

__global__ __launch_bounds__(256, 4) void k_attn(
    const f16* __restrict__ Q, const f16* __restrict__ K,
    const f16* __restrict__ Vt, const float* __restrict__ vmb,
    f16* __restrict__ attnA) {
  __shared__ f16 Kl[2][KBc * 64];
  __shared__ f16 Vl[2][HSz * 64];
  __shared__ float mbl[2][KBc];
  const int t = threadIdx.x, lane = t & 63, wv = t >> 6;
  const int ll = lane & 15, lh = lane >> 4;
  const int bh = blockIdx.y, b = bh >> 4, h = bh & 15;
  const int q0 = blockIdx.x * QB;
  const size_t base = (size_t)bh * Sz * HSz;

  f16x8 qf[2];
  {
    const f16* Qb = Q + base + (size_t)(q0 + wv * 16 + ll) * HSz;
    qf[0] = *reinterpret_cast<const f16x8*>(&Qb[lh * 8]);
    qf[1] = *reinterpret_cast<const f16x8*>(&Qb[32 + lh * 8]);
  }

  f32x4 acc[4] = {};
  float m_run = NEGB, l_run = 0.f;

  auto stage = [&](int key0, int buf) {
#pragma unroll
    for (int j = 0; j < 2; ++j) {
      int c = (wv * 2 + j) * 64 + lane;
      int r = c >> 3, p = c & 7, ps = (p ^ (r & 7)) * 8;
      gload16(K + base + (size_t)(key0 + r) * HSz + ps, (char*)&Kl[buf][0] + c * 16);
      gload16(Vt + base + (size_t)r * Sz + key0 + ps, (char*)&Vl[buf][0] + c * 16);
    }
    if (wv == 0)
      gload4(vmb + b * Sz + key0 + lane, (char*)&mbl[buf][0] + lane * 4);
  };

  stage(0, 0);
  __syncthreads();

  for (int kt = 0; kt < NT; ++kt) {
    const int cur = kt & 1;
    if (kt + 1 < NT) stage((kt + 1) * KBc, cur ^ 1);

    // S^T = K * Q^T
    f32x4 sa[4] = {};
    __builtin_amdgcn_s_setprio(1);
#pragma unroll
    for (int cf = 0; cf < 4; ++cf) {
      const int row = cf * 16 + ll;
      const f16* kr = &Kl[cur][row * 64];
      f16x8 ka0 = *reinterpret_cast<const f16x8*>(&kr[(lh ^ (ll & 7)) * 8]);
      f16x8 ka1 = *reinterpret_cast<const f16x8*>(&kr[((4 + lh) ^ (ll & 7)) * 8]);
      sa[cf] = MFMA32(ka0, qf[0], sa[cf]);
      sa[cf] = MFMA32(ka1, qf[1], sa[cf]);
    }
    __builtin_amdgcn_s_setprio(0);

    // masked scores + online softmax with defer-max (one query per lane)
    float s[4][4];
    float mx = NEGB;
#pragma unroll
    for (int cf = 0; cf < 4; ++cf) {
      f32x4 mb = *reinterpret_cast<const f32x4*>(&mbl[cur][cf * 16 + lh * 4]);
#pragma unroll
      for (int i = 0; i < 4; ++i) {
        s[cf][i] = sa[cf][i] + mb[i];
        mx = fmaxf(mx, s[cf][i]);
      }
    }
    mx = fmaxf(mx, __shfl_xor(mx, 16));
    mx = fmaxf(mx, __shfl_xor(mx, 32));
    if (__any(mx > m_run + 8.f)) {
      const float nm = fmaxf(m_run, mx);
      const float sc = EXP2(m_run - nm);
      m_run = nm;
      l_run *= sc;
#pragma unroll
      for (int hf = 0; hf < 4; ++hf)
#pragma unroll
        for (int i = 0; i < 4; ++i) acc[hf][i] *= sc;
    }
    float rs = 0.f;
    f16x4 pb[4];
#pragma unroll
    for (int cf = 0; cf < 4; ++cf) {
      float p0 = EXP2(s[cf][0] - m_run), p1 = EXP2(s[cf][1] - m_run);
      float p2 = EXP2(s[cf][2] - m_run), p3 = EXP2(s[cf][3] - m_run);
      rs += (p0 + p1) + (p2 + p3);
      pb[cf][0] = (f16)p0; pb[cf][1] = (f16)p1;
      pb[cf][2] = (f16)p2; pb[cf][3] = (f16)p3;
    }
    rs += __shfl_xor(rs, 16);
    rs += __shfl_xor(rs, 32);
    l_run += rs;

    // O^T += V^T * P^T  (16x16x16: P^T D-layout == B-layout)
    __builtin_amdgcn_s_setprio(1);
#pragma unroll
    for (int hf = 0; hf < 4; ++hf) {
      const int row = hf * 16 + ll;
      const f16* vr = &Vl[cur][row * 64];
#pragma unroll
      for (int cf = 0; cf < 4; ++cf) {
        f16x4 va = *reinterpret_cast<const f16x4*>(
            &vr[((2 * cf + (lh >> 1)) ^ (ll & 7)) * 8 + (lh & 1) * 4]);
        acc[hf] = MFMA16(va, pb[cf], acc[hf]);
      }
    }
    __builtin_amdgcn_s_setprio(0);
    __syncthreads();  // drains vmcnt: next buffer staged; cur safe to overwrite
  }

  const float inv = 1.f / fmaxf(l_run, 1e-30f);
  const int q = q0 + wv * 16 + ll;
  f16* orow = attnA + (size_t)(b * Sz + q) * (Hz * HSz) + h * HSz;
#pragma unroll
  for (int hf = 0; hf < 4; ++hf) {
    f16x4 ov;
#pragma unroll
    for (int i = 0; i < 4; ++i) ov[i] = (f16)(acc[hf][i] * inv);
    *reinterpret_cast<f16x4*>(&orow[hf * 16 + 4 * lh]) = ov;
  }
}

extern "C" void kernel_launch(void* const* d_in, const int* in_sizes, int n_in,
                              void* d_out, int out_size, void* d_ws, size_t ws_size,
                              hipStream_t stream) {
  const float* query = (const float*)d_in[0];
  const float* key   = (const float*)d_in[1];
  const float* value = (const float*)d_in[2];
  const float* Wq = (const float*)d_in[3];
  const float* bq = (const float*)d_in[4];
  const float* Wk = (const float*)d_in[5];
  const float* bk = (const float*)d_in[6];
  const float* Wv = (const float*)d_in[7];
  const float* bv = (const float*)d_in[8];
  const float* Wo = (const float*)d_in[9];
  const float* bo = (const float*)d_in[10];
  const int* qm = (const int*)d_in[11];
  const int* vm = (const int*)d_in[12];

  // workspace layout (f16 elements)
  f16* Xq  = (f16*)d_ws;
  f16* Xk  = Xq + 4194304;
  f16* Xv  = Xk + 4194304;
  f16* Wqh = Xv + 4194304;
  f16* Wql = Wqh + 1048576;   // reused as vmbias (f32[4096])
  f16* Wkh = Wql + 1048576;
  f16* Wkl = Wkh + 1048576;   // unused
  f16* Wvh = Wkl + 1048576;
  f16* Wvl = Wvh + 1048576;   // unused
  f16* Woh = Wvl + 1048576;
  f16* Wol = Woh + 1048576;   // unused
  f16* Qh  = Wol + 1048576;
  f16* Kh  = Qh + 4194304;
  f16* Vth = Kh + 4194304;
  f16* Ah  = Vth + 4194304;
  float* vmbias = (float*)Wql;

  k_cvt<<<4096, 256, 0, stream>>>(query, Xq, Mz * Dz);
  k_cvt<<<4096, 256, 0, stream>>>(key,   Xk, Mz * Dz);
  k_cvt<<<4096, 256, 0, stream>>>(value, Xv, Mz * Dz);
  k_mask<<<16, 256, 0, stream>>>(vm, vmbias);

  dim3 wg(32, 32);
  k_wsplit<<<wg, 256, 0, stream>>>(Wq, Wqh);
  k_wsplit<<<wg, 256, 0, stream>>>(Wk, Wkh);
  k_wsplit<<<wg, 256, 0, stream>>>(Wv, Wvh);
  k_wsplit<<<wg, 256, 0, stream>>>(Wo, Woh);

  dim3 gg(Dz / BNg, Mz / BMg);  // (8, 32)
  k_gemm<0><<<gg, 512, 0, stream>>>(Xq, Wqh, bq, Qh, nullptr, nullptr, QSCALE);
  k_gemm<0><<<gg, 512, 0, stream>>>(Xk, Wkh, bk, Kh, nullptr, nullptr, 1.0f);
  k_gemm<1><<<gg, 512, 0, stream>>>(Xv, Wvh, bv, Vth, nullptr, nullptr, 1.0f);

  dim3 ag(Sz / QB, Bz * Hz);  // (32, 32)
  k_attn<<<ag, 256, 0, stream>>>(Qh, Kh, Vth, vmbias, Ah);

  k_gemm<2><<<gg, 512, 0, stream>>>(Ah, Woh, bo, nullptr, (float*)d_out, qm, 1.0f);
}

// Round 5
// 151.244 us; speedup vs baseline: 1.6561x; 1.0404x over previous
//
#include <hip/hip_runtime.h>

#define Bz 2
#define Sz 2048
#define Dz 1024
#define Hz 16
#define HSz 64
#define Mz 4096
#define NEGB (-1e30f)
#define QSCALE (0.125f * 1.44269504088896f)  // fold 1/sqrt(64) and log2(e) into Q

typedef _Float16 f16;
typedef _Float16 f16x8 __attribute__((ext_vector_type(8)));
typedef _Float16 f16x4 __attribute__((ext_vector_type(4)));
typedef float f32x4 __attribute__((ext_vector_type(4)));

#define MFMA32(a, b, c) __builtin_amdgcn_mfma_f32_16x16x32_f16((a), (b), (c), 0, 0, 0)
#define MFMA16(a, b, c) __builtin_amdgcn_mfma_f32_16x16x16f16((a), (b), (c), 0, 0, 0)
#define EXP2(x) __builtin_amdgcn_exp2f(x)

__device__ __forceinline__ void gload16(const void* g, void* l) {
  __builtin_amdgcn_global_load_lds(
      (const __attribute__((address_space(1))) unsigned int*)(unsigned long long)g,
      (__attribute__((address_space(3))) unsigned int*)(unsigned int)(unsigned long long)l,
      16, 0, 0);
}
__device__ __forceinline__ void gload4(const void* g, void* l) {
  __builtin_amdgcn_global_load_lds(
      (const __attribute__((address_space(1))) unsigned int*)(unsigned long long)g,
      (__attribute__((address_space(3))) unsigned int*)(unsigned int)(unsigned long long)l,
      4, 0, 0);
}

// ---------------- fp32 -> fp16 convert, 3 tensors in one dispatch ----------------
__global__ __launch_bounds__(256) void k_cvt3(const float* __restrict__ a,
                                              const float* __restrict__ b,
                                              const float* __restrict__ c,
                                              f16* __restrict__ oa,
                                              f16* __restrict__ ob,
                                              f16* __restrict__ oc) {
  const float* in = blockIdx.y == 0 ? a : blockIdx.y == 1 ? b : c;
  f16* out = blockIdx.y == 0 ? oa : blockIdx.y == 1 ? ob : oc;
  int i = (blockIdx.x * 256 + threadIdx.x) * 4;
  f32x4 v = *reinterpret_cast<const f32x4*>(in + i);
  f16x4 o;
  o[0] = (f16)v[0]; o[1] = (f16)v[1]; o[2] = (f16)v[2]; o[3] = (f16)v[3];
  *reinterpret_cast<f16x4*>(out + i) = o;
}

// ---------------- v_mask -> f32 additive bias (exp2 domain) ----------------
__global__ __launch_bounds__(256) void k_mask(const int* __restrict__ vm,
                                              float* __restrict__ out) {
  int i = blockIdx.x * 256 + threadIdx.x;
  if (i < Bz * Sz) out[i] = vm[i] ? 0.f : NEGB;
}

// ---------------- W [K][N] fp32 -> Wt [N][K] fp16, 4 weights in one dispatch ----------------
__global__ __launch_bounds__(256) void k_wsplit4(
    const float* __restrict__ W0, const float* __restrict__ W1,
    const float* __restrict__ W2, const float* __restrict__ W3,
    f16* __restrict__ T0, f16* __restrict__ T1, f16* __restrict__ T2,
    f16* __restrict__ T3) {
  const int z = blockIdx.z;
  const float* W = z == 0 ? W0 : z == 1 ? W1 : z == 2 ? W2 : W3;
  f16* T = z == 0 ? T0 : z == 1 ? T1 : z == 2 ? T2 : T3;
  __shared__ float t[32][33];
  const int tx = threadIdx.x & 31, ty = threadIdx.x >> 5;
  const int n0 = blockIdx.x * 32, k0 = blockIdx.y * 32;
#pragma unroll
  for (int r = 0; r < 4; ++r)
    t[ty * 4 + r][tx] = W[(size_t)(k0 + ty * 4 + r) * Dz + n0 + tx];
  __syncthreads();
#pragma unroll
  for (int r = 0; r < 4; ++r)
    T[(size_t)(n0 + ty * 4 + r) * Dz + k0 + tx] = (f16)t[tx][ty * 4 + r];
}

// ---------------- GEMM main-loop (shared by QKV / O kernels) ----------------
// 128x128 tile, BK=64, 512 threads (8 waves 2x4), double-buffered LDS,
// XOR-swizzled staging source + swizzled ds_read (conflict-free b128).
#define BMg 128
#define BNg 128
#define BKg 64

#define GEMM_MAINLOOP(Aptr, Bptr)                                              \
  f32x4 acc[4][2] = {};                                                        \
  auto stage = [&](int kt, int buf) {                                          \
    const int k0 = kt * BKg;                                                   \
    _Pragma("unroll") for (int j = 0; j < 2; ++j) {                            \
      int c = j * 512 + t;                                                     \
      int row = c >> 3, p = c & 7;                                             \
      int ke = (p ^ (row & 7)) * 8;                                            \
      gload16(Aptr + (size_t)(m0 + row) * Dz + k0 + ke,                        \
              (char*)&As[buf][0] + c * 16);                                    \
      gload16(Bptr + (size_t)(n0 + row) * Dz + k0 + ke,                        \
              (char*)&Bs[buf][0] + c * 16);                                    \
    }                                                                          \
  };                                                                           \
  stage(0, 0);                                                                 \
  __syncthreads();                                                             \
  for (int kt = 0; kt < Dz / BKg; ++kt) {                                      \
    const int cur = kt & 1;                                                    \
    if (kt + 1 < Dz / BKg) stage(kt + 1, cur ^ 1);                             \
    __builtin_amdgcn_s_setprio(1);                                             \
    _Pragma("unroll") for (int ks = 0; ks < 2; ++ks) {                         \
      f16x8 af[4], bf[2];                                                      \
      _Pragma("unroll") for (int fr = 0; fr < 4; ++fr) {                       \
        const int row = wr * 64 + fr * 16 + ll;                                \
        af[fr] = *reinterpret_cast<const f16x8*>(                              \
            &As[cur][row * 64 + (((ks * 4 + lh) ^ (row & 7)) * 8)]);           \
      }                                                                        \
      _Pragma("unroll") for (int fc = 0; fc < 2; ++fc) {                       \
        const int col = wc * 32 + fc * 16 + ll;                                \
        bf[fc] = *reinterpret_cast<const f16x8*>(                              \
            &Bs[cur][col * 64 + (((ks * 4 + lh) ^ (col & 7)) * 8)]);           \
      }                                                                        \
      _Pragma("unroll") for (int fr = 0; fr < 4; ++fr)                         \
          _Pragma("unroll") for (int fc = 0; fc < 2; ++fc)                     \
              acc[fr][fc] = MFMA32(af[fr], bf[fc], acc[fr][fc]);               \
    }                                                                          \
    __builtin_amdgcn_s_setprio(0);                                             \
    __syncthreads();                                                           \
  }

// Merged Q/K/V projection GEMM: blockIdx.z selects input/weight/output.
// z=0: Q (scaled, [b][h][tok][hs]); z=1: K (same layout); z=2: V ([b][h][hs][tok])
__global__ __launch_bounds__(512) void k_gemm_qkv(
    const f16* __restrict__ Xq, const f16* __restrict__ Xk,
    const f16* __restrict__ Xv, const f16* __restrict__ Wq,
    const f16* __restrict__ Wk, const f16* __restrict__ Wv,
    const float* __restrict__ bq, const float* __restrict__ bk,
    const float* __restrict__ bv, f16* __restrict__ Qh, f16* __restrict__ Kh,
    f16* __restrict__ Vth) {
  __shared__ f16 As[2][BMg * BKg];
  __shared__ f16 Bs[2][BNg * BKg];
  const int z = blockIdx.z;
  const f16* A = z == 0 ? Xq : z == 1 ? Xk : Xv;
  const f16* Bt = z == 0 ? Wq : z == 1 ? Wk : Wv;
  const float* bias = z == 0 ? bq : z == 1 ? bk : bv;
  f16* outh = z == 0 ? Qh : z == 1 ? Kh : Vth;
  const float oscale = z == 0 ? QSCALE : 1.0f;
  const int t = threadIdx.x, lane = t & 63, wv = t >> 6;
  const int ll = lane & 15, lh = lane >> 4;
  const int m0 = blockIdx.y * BMg, n0 = blockIdx.x * BNg;
  const int wr = wv >> 2, wc = wv & 3;

  GEMM_MAINLOOP(A, Bt)

#pragma unroll
  for (int fc = 0; fc < 2; ++fc) {
    const int n = n0 + wc * 32 + fc * 16 + ll;
    const float bn = bias[n];
#pragma unroll
    for (int fr = 0; fr < 4; ++fr)
#pragma unroll
      for (int i = 0; i < 4; ++i) {
        const int m = m0 + wr * 64 + fr * 16 + lh * 4 + i;
        float v = (acc[fr][fc][i] + bn) * oscale;
        if (z < 2) {
          outh[((size_t)((m >> 11) * Hz + (n >> 6))) * (Sz * HSz) +
               (size_t)(m & (Sz - 1)) * HSz + (n & 63)] = (f16)v;
        } else {
          outh[((size_t)((m >> 11) * Hz + (n >> 6))) * (HSz * Sz) +
               (size_t)(n & 63) * Sz + (m & (Sz - 1))] = (f16)v;
        }
      }
  }
}

// Output projection GEMM: f32 out, * q_mask[row]
__global__ __launch_bounds__(512) void k_gemm_o(
    const f16* __restrict__ A, const f16* __restrict__ Bt,
    const float* __restrict__ bias, float* __restrict__ outf,
    const int* __restrict__ qmask) {
  __shared__ f16 As[2][BMg * BKg];
  __shared__ f16 Bs[2][BNg * BKg];
  const int t = threadIdx.x, lane = t & 63, wv = t >> 6;
  const int ll = lane & 15, lh = lane >> 4;
  const int m0 = blockIdx.y * BMg, n0 = blockIdx.x * BNg;
  const int wr = wv >> 2, wc = wv & 3;

  GEMM_MAINLOOP(A, Bt)

#pragma unroll
  for (int fc = 0; fc < 2; ++fc) {
    const int n = n0 + wc * 32 + fc * 16 + ll;
    const float bn = bias[n];
#pragma unroll
    for (int fr = 0; fr < 4; ++fr)
#pragma unroll
      for (int i = 0; i < 4; ++i) {
        const int m = m0 + wr * 64 + fr * 16 + lh * 4 + i;
        outf[(size_t)m * Dz + n] = (acc[fr][fc][i] + bn) * (float)qmask[m];
      }
  }
}

// ---------------- flash attention, S^T structure ----------------
// Q,K: [bh][token][hs] f16; Vt: [bh][hs][token] f16; vmb: [b][token] f32 bias.
// 8 waves x 16 queries = QB 128. Per wave: S^T = mfma32(K_frag, Q_frag): lane
// holds 16 key-scores of ONE query (q = ll). Softmax in-register (defer-max).
// P^T D-layout == B-layout of mfma 16x16x16 -> PV directly, no LDS round-trip.
#define QB 128
#define KBc 64
#define NT (Sz / KBc)

__global__ __launch_bounds__(512, 4) void k_attn(
    const f16* __restrict__ Q, const f16* __restrict__ K,
    const f16* __restrict__ Vt, const float* __restrict__ vmb,
    f16* __restrict__ attnA) {
  __shared__ f16 Kl[2][KBc * 64];
  __shared__ f16 Vl[2][HSz * 64];
  __shared__ float mbl[2][KBc];
  const int t = threadIdx.x, lane = t & 63, wv = t >> 6;
  const int ll = lane & 15, lh = lane >> 4;
  const int bh = blockIdx.y, b = bh >> 4, h = bh & 15;
  const int q0 = blockIdx.x * QB;
  const size_t base = (size_t)bh * Sz * HSz;

  f16x8 qf[2];
  {
    const f16* Qb = Q + base + (size_t)(q0 + wv * 16 + ll) * HSz;
    qf[0] = *reinterpret_cast<const f16x8*>(&Qb[lh * 8]);
    qf[1] = *reinterpret_cast<const f16x8*>(&Qb[32 + lh * 8]);
  }

  f32x4 acc[4] = {};
  float m_run = NEGB, l_run = 0.f;

  // stage tile key0 into buffer buf (8 waves: 1 K + 1 V chunk each)
  auto stage = [&](int key0, int buf) {
    int c = wv * 64 + lane;
    int r = c >> 3, p = c & 7, ps = (p ^ (r & 7)) * 8;
    gload16(K + base + (size_t)(key0 + r) * HSz + ps, (char*)&Kl[buf][0] + c * 16);
    gload16(Vt + base + (size_t)r * Sz + key0 + ps, (char*)&Vl[buf][0] + c * 16);
    if (wv == 0)
      gload4(vmb + b * Sz + key0 + lane, (char*)&mbl[buf][0] + lane * 4);
  };

  stage(0, 0);
  __syncthreads();

  for (int kt = 0; kt < NT; ++kt) {
    const int cur = kt & 1;
    if (kt + 1 < NT) stage((kt + 1) * KBc, cur ^ 1);

    // S^T = K * Q^T
    f32x4 sa[4] = {};
    __builtin_amdgcn_s_setprio(1);
#pragma unroll
    for (int cf = 0; cf < 4; ++cf) {
      const int row = cf * 16 + ll;
      const f16* kr = &Kl[cur][row * 64];
      f16x8 ka0 = *reinterpret_cast<const f16x8*>(&kr[(lh ^ (ll & 7)) * 8]);
      f16x8 ka1 = *reinterpret_cast<const f16x8*>(&kr[((4 + lh) ^ (ll & 7)) * 8]);
      sa[cf] = MFMA32(ka0, qf[0], sa[cf]);
      sa[cf] = MFMA32(ka1, qf[1], sa[cf]);
    }
    __builtin_amdgcn_s_setprio(0);

    // masked scores + online softmax with defer-max (one query per lane)
    float s[4][4];
    float mx = NEGB;
#pragma unroll
    for (int cf = 0; cf < 4; ++cf) {
      f32x4 mb = *reinterpret_cast<const f32x4*>(&mbl[cur][cf * 16 + lh * 4]);
#pragma unroll
      for (int i = 0; i < 4; ++i) {
        s[cf][i] = sa[cf][i] + mb[i];
        mx = fmaxf(mx, s[cf][i]);
      }
    }
    mx = fmaxf(mx, __shfl_xor(mx, 16));
    mx = fmaxf(mx, __shfl_xor(mx, 32));
    if (__any(mx > m_run + 8.f)) {
      const float nm = fmaxf(m_run, mx);
      const float sc = EXP2(m_run - nm);
      m_run = nm;
      l_run *= sc;
#pragma unroll
      for (int hf = 0; hf < 4; ++hf)
#pragma unroll
        for (int i = 0; i < 4; ++i) acc[hf][i] *= sc;
    }
    float rs = 0.f;
    f16x4 pb[4];
#pragma unroll
    for (int cf = 0; cf < 4; ++cf) {
      float p0 = EXP2(s[cf][0] - m_run), p1 = EXP2(s[cf][1] - m_run);
      float p2 = EXP2(s[cf][2] - m_run), p3 = EXP2(s[cf][3] - m_run);
      rs += (p0 + p1) + (p2 + p3);
      pb[cf][0] = (f16)p0; pb[cf][1] = (f16)p1;
      pb[cf][2] = (f16)p2; pb[cf][3] = (f16)p3;
    }
    rs += __shfl_xor(rs, 16);
    rs += __shfl_xor(rs, 32);
    l_run += rs;

    // O^T += V^T * P^T  (16x16x16: P^T D-layout == B-layout)
    __builtin_amdgcn_s_setprio(1);
#pragma unroll
    for (int hf = 0; hf < 4; ++hf) {
      const int row = hf * 16 + ll;
      const f16* vr = &Vl[cur][row * 64];
#pragma unroll
      for (int cf = 0; cf < 4; ++cf) {
        f16x4 va = *reinterpret_cast<const f16x4*>(
            &vr[((2 * cf + (lh >> 1)) ^ (ll & 7)) * 8 + (lh & 1) * 4]);
        acc[hf] = MFMA16(va, pb[cf], acc[hf]);
      }
    }
    __builtin_amdgcn_s_setprio(0);
    __syncthreads();  // drains vmcnt: next buffer staged; cur safe to overwrite
  }

  const float inv = 1.f / fmaxf(l_run, 1e-30f);
  const int q = q0 + wv * 16 + ll;
  f16* orow = attnA + (size_t)(b * Sz + q) * (Hz * HSz) + h * HSz;
#pragma unroll
  for (int hf = 0; hf < 4; ++hf) {
    f16x4 ov;
#pragma unroll
    for (int i = 0; i < 4; ++i) ov[i] = (f16)(acc[hf][i] * inv);
    *reinterpret_cast<f16x4*>(&orow[hf * 16 + 4 * lh]) = ov;
  }
}

extern "C" void kernel_launch(void* const* d_in, const int* in_sizes, int n_in,
                              void* d_out, int out_size, void* d_ws, size_t ws_size,
                              hipStream_t stream) {
  const float* query = (const float*)d_in[0];
  const float* key   = (const float*)d_in[1];
  const float* value = (const float*)d_in[2];
  const float* Wq = (const float*)d_in[3];
  const float* bq = (const float*)d_in[4];
  const float* Wk = (const float*)d_in[5];
  const float* bk = (const float*)d_in[6];
  const float* Wv = (const float*)d_in[7];
  const float* bv = (const float*)d_in[8];
  const float* Wo = (const float*)d_in[9];
  const float* bo = (const float*)d_in[10];
  const int* qm = (const int*)d_in[11];
  const int* vm = (const int*)d_in[12];

  // workspace layout (f16 elements)
  f16* Xq  = (f16*)d_ws;
  f16* Xk  = Xq + 4194304;
  f16* Xv  = Xk + 4194304;
  f16* Wqh = Xv + 4194304;
  f16* Wkh = Wqh + 1048576;
  f16* Wvh = Wkh + 1048576;
  f16* Woh = Wvh + 1048576;
  f16* Qh  = Woh + 1048576;
  f16* Kh  = Qh + 4194304;
  f16* Vth = Kh + 4194304;
  f16* Ah  = Vth + 4194304;
  float* vmbias = (float*)(Ah + 4194304);  // f32[4096]

  dim3 cg(4096, 3);
  k_cvt3<<<cg, 256, 0, stream>>>(query, key, value, Xq, Xk, Xv);
  k_mask<<<16, 256, 0, stream>>>(vm, vmbias);

  dim3 wg(32, 32, 4);
  k_wsplit4<<<wg, 256, 0, stream>>>(Wq, Wk, Wv, Wo, Wqh, Wkh, Wvh, Woh);

  dim3 gq(Dz / BNg, Mz / BMg, 3);  // (8, 32, 3)
  k_gemm_qkv<<<gq, 512, 0, stream>>>(Xq, Xk, Xv, Wqh, Wkh, Wvh, bq, bk, bv,
                                     Qh, Kh, Vth);

  dim3 ag(Sz / QB, Bz * Hz);  // (16, 32)
  k_attn<<<ag, 512, 0, stream>>>(Qh, Kh, Vth, vmbias, Ah);

  dim3 gg(Dz / BNg, Mz / BMg);  // (8, 32)
  k_gemm_o<<<gg, 512, 0, stream>>>(Ah, Woh, bo, (float*)d_out, qm);
}